// Round 1
// baseline (346.694 us; speedup 1.0000x reference)
//
#include <hip/hip_runtime.h>

#define SEQ   2048
#define BATCH 2
#define HID   2048
#define NHEAD 16
#define HDIM  128
#define MTOT  4096
#define KDIM  2048

typedef __attribute__((ext_vector_type(8))) short  bf16x8;
typedef __attribute__((ext_vector_type(4))) float  f32x4;
typedef __attribute__((ext_vector_type(4))) unsigned short u16x4;
typedef __attribute__((ext_vector_type(8))) unsigned short u16x8;

__device__ __forceinline__ unsigned short f2bf(float x) {
  unsigned u = __float_as_uint(x);
  u += 0x7fffu + ((u >> 16) & 1u);
  return (unsigned short)(u >> 16);
}

__device__ __forceinline__ void gl_lds16(const void* g, void* l) {
  __builtin_amdgcn_global_load_lds(
      (__attribute__((address_space(1))) void*)g,
      (__attribute__((address_space(3))) void*)l, 16, 0, 0);
}

__device__ __forceinline__ f32x4 mfma16(bf16x8 a, bf16x8 b, f32x4 c) {
  return __builtin_amdgcn_mfma_f32_16x16x32_bf16(a, b, c, 0, 0, 0);
}

// fp32 -> bf16 with K-granule swizzle (rows of length 2048):
// element (r,k) stored at r*2048 + (k ^ (((r>>1)&3)<<3))
__global__ __launch_bounds__(256, 8)
void conv_swz(const float* __restrict__ src, unsigned short* __restrict__ dst) {
  int i = blockIdx.x * 256 + threadIdx.x;
  int base = i << 2;
  int r = base >> 11, k = base & 2047;
  f32x4 v = *(const f32x4*)(src + base);
  int kp = k ^ (((r >> 1) & 3) << 3);
  u16x4 o;
  o[0] = f2bf(v[0]); o[1] = f2bf(v[1]); o[2] = f2bf(v[2]); o[3] = f2bf(v[3]);
  *(u16x4*)(dst + (size_t)r * 2048 + kp) = o;
}

__global__ __launch_bounds__(256, 8)
void rope_cache_k(float* __restrict__ cosT, float* __restrict__ sinT) {
  int idx = blockIdx.x * 256 + threadIdx.x;   // 2048*64
  int s = idx >> 6, i = idx & 63;
  float inv = powf(1e-4f, (float)i * (1.0f / 64.0f));
  float a = (float)s * inv;
  cosT[idx] = cosf(a);
  sinT[idx] = sinf(a);
}

// NT GEMM: C[m][n] = sum_k A[m][k]*Bt[n][k], K=2048, tile 128x128, BK=32.
// A/Bt are bf16 with the conv_swz granule swizzle.
// EPI=0: QKV epilogue (bias+RoPE -> Qs/Ks swizzled [b,nh,s,d], V plain).
// EPI=1: dense epilogue (bias -> fp32 Cout, ctx-swizzle assumed on A side only).
template<int EPI>
__global__ __launch_bounds__(256, 2)
void gemm_nt(const unsigned short* __restrict__ A,
             const unsigned short* __restrict__ Bt,
             const float* __restrict__ bias,
             unsigned short* __restrict__ Qs,
             unsigned short* __restrict__ Ks,
             unsigned short* __restrict__ Vp,
             const float* __restrict__ cosT,
             const float* __restrict__ sinT,
             float* __restrict__ Cout)
{
  __shared__ alignas(16) unsigned short Alds[128 * 32];
  __shared__ alignas(16) unsigned short Blds[128 * 32];
  const int tid = threadIdx.x;
  const int w = tid >> 6;
  const int lane = tid & 63;
  const int g = lane >> 4, c = lane & 15;
  const int m0 = blockIdx.y << 7, n0 = blockIdx.x << 7;

  const char* Ag = (const char*)A + (size_t)(m0 + (tid >> 2)) * (KDIM * 2) + (tid & 3) * 16;
  const char* Bg = (const char*)Bt + (size_t)(n0 + (tid >> 2)) * (KDIM * 2) + (tid & 3) * 16;
  char* AldsW = (char*)Alds + w * 1024;
  char* BldsW = (char*)Blds + w * 1024;

  f32x4 acc[2][8];
#pragma unroll
  for (int i = 0; i < 2; ++i)
#pragma unroll
    for (int j = 0; j < 8; ++j) {
      acc[i][j][0] = 0.f; acc[i][j][1] = 0.f; acc[i][j][2] = 0.f; acc[i][j][3] = 0.f;
    }

  for (int k0 = 0; k0 < KDIM; k0 += 32) {
    __syncthreads();
    gl_lds16(Ag + k0 * 2,          AldsW);
    gl_lds16(Ag + k0 * 2 + 262144, AldsW + 4096);
    gl_lds16(Bg + k0 * 2,          BldsW);
    gl_lds16(Bg + k0 * 2 + 262144, BldsW + 4096);
    __syncthreads();
    bf16x8 af[2], bfr[8];
#pragma unroll
    for (int fr = 0; fr < 2; ++fr) {
      int rl = w * 32 + fr * 16 + c;
      int off = rl * 64 + ((g ^ ((rl >> 1) & 3)) << 4);
      af[fr] = *(const bf16x8*)((const char*)Alds + off);
    }
#pragma unroll
    for (int fn = 0; fn < 8; ++fn) {
      int rl = fn * 16 + c;
      int off = rl * 64 + ((g ^ ((rl >> 1) & 3)) << 4);
      bfr[fn] = *(const bf16x8*)((const char*)Blds + off);
    }
#pragma unroll
    for (int fr = 0; fr < 2; ++fr)
#pragma unroll
      for (int fn = 0; fn < 8; ++fn)
        acc[fr][fn] = mfma16(af[fr], bfr[fn], acc[fr][fn]);
  }

  if (EPI == 0) {
    const int nh = n0 / 384;
    const int type = (n0 % 384) >> 7;   // 0=q, 1=k, 2=v
    if (type < 2) {
      unsigned short* dst = (type == 0) ? Qs : Ks;
      const float qsc = (type == 0) ? 0.08838834764831845f : 1.0f; // 1/sqrt(128) folded into Q
#pragma unroll
      for (int fr = 0; fr < 2; ++fr)
#pragma unroll
        for (int r = 0; r < 4; ++r) {
          int m = m0 + w * 32 + fr * 16 + g * 4 + r;
          int s = m >> 1, b = m & 1;
          size_t plane = (size_t)(b * NHEAD + nh) * (SEQ * HDIM);
          int swb = (s & 7) << 3;
#pragma unroll
          for (int fn = 0; fn < 4; ++fn) {
            int dl = fn * 16 + c;                      // 0..63
            float xl = acc[fr][fn][r]     + bias[n0 + dl];
            float xr = acc[fr][fn + 4][r] + bias[n0 + 64 + dl];
            float co = cosT[s * 64 + dl];
            float si = sinT[s * 64 + dl];
            float ol  = (co * xl - si * xr) * qsc;
            float orr = (si * xl + co * xr) * qsc;
            dst[plane + (size_t)s * HDIM + (dl ^ swb)]        = f2bf(ol);
            dst[plane + (size_t)s * HDIM + ((dl + 64) ^ swb)] = f2bf(orr);
          }
        }
    } else {
#pragma unroll
      for (int fr = 0; fr < 2; ++fr)
#pragma unroll
        for (int r = 0; r < 4; ++r) {
          int m = m0 + w * 32 + fr * 16 + g * 4 + r;
          int s = m >> 1, b = m & 1;
          size_t plane = (size_t)(b * NHEAD + nh) * (SEQ * HDIM);
#pragma unroll
          for (int fn = 0; fn < 8; ++fn) {
            int d = fn * 16 + c;
            float x = acc[fr][fn][r] + bias[n0 + d];
            Vp[plane + (size_t)s * HDIM + d] = f2bf(x);
          }
        }
    }
  } else {
#pragma unroll
    for (int fr = 0; fr < 2; ++fr)
#pragma unroll
      for (int r = 0; r < 4; ++r) {
        int m = m0 + w * 32 + fr * 16 + g * 4 + r;
#pragma unroll
        for (int fn = 0; fn < 8; ++fn) {
          int n = n0 + fn * 16 + c;
          Cout[(size_t)m * HID + n] = acc[fr][fn][r] + bias[n];
        }
      }
  }
}

// V [plane][t][d] -> Vt [plane][d][t], t-granule swizzled: (t ^ ((d&7)<<3))
__global__ __launch_bounds__(256, 4)
void transpose_v(const unsigned short* __restrict__ Vp, unsigned short* __restrict__ Vt) {
  __shared__ alignas(16) unsigned short T[64 * 136];
  const int plane = blockIdx.x >> 5;
  const int t0 = (blockIdx.x & 31) << 6;
  const size_t pbase = (size_t)plane * (SEQ * HDIM);
  const int tid = threadIdx.x;
  {
    int t = tid >> 2, d0 = (tid & 3) << 5;
    const unsigned short* src = Vp + pbase + (size_t)(t0 + t) * HDIM + d0;
#pragma unroll
    for (int j = 0; j < 4; ++j) {
      u16x8 v = *(const u16x8*)(src + j * 8);
      *(u16x8*)(&T[t * 136 + d0 + j * 8]) = v;
    }
  }
  __syncthreads();
  {
    int d = tid >> 1, half = tid & 1;
    unsigned short* dstp = Vt + pbase + (size_t)d * SEQ;
    int swb = (d & 7) << 3;
#pragma unroll
    for (int gg = 0; gg < 4; ++gg) {
      u16x8 v;
#pragma unroll
      for (int e = 0; e < 8; ++e)
        v[e] = T[(half * 32 + gg * 8 + e) * 136 + d];
      int tloc = half * 32 + gg * 8;
      *(u16x8*)(dstp + ((t0 + tloc) ^ swb)) = v;
    }
  }
}

// Flash attention. 512 blocks: blockIdx.x = (15-qb)*32 + head (heavy first).
// Q in regs; K/Vt LDS-staged per 64-kv tile; online softmax; ctx bf16 with
// dense-GEMM A-side granule swizzle.
__global__ __launch_bounds__(256, 2)
void attn(const unsigned short* __restrict__ Qs,
          const unsigned short* __restrict__ Ks,
          const unsigned short* __restrict__ Vt,
          unsigned short* __restrict__ ctx)
{
  __shared__ alignas(16) unsigned short Klds[64 * 128];
  __shared__ alignas(16) unsigned short Vlds[128 * 64];
  __shared__ alignas(16) unsigned short Plds[128 * 72];
  const int tid = threadIdx.x;
  const int w = tid >> 6, lane = tid & 63, g = lane >> 4, c = lane & 15;
  const int head = blockIdx.x & 31;
  const int qb = 15 - (blockIdx.x >> 5);
  const int q0 = qb << 7;
  const size_t plane = (size_t)head * (SEQ * HDIM);
  const unsigned short* Qp = Qs + plane;
  const unsigned short* Kp = Ks + plane;
  const unsigned short* Vp = Vt + plane;

  bf16x8 qf[2][4];
#pragma unroll
  for (int fr = 0; fr < 2; ++fr) {
    int s = q0 + w * 32 + fr * 16 + c;
    int swb = (s & 7) << 3;
#pragma unroll
    for (int kk = 0; kk < 4; ++kk) {
      int d0 = kk * 32 + g * 8;
      qf[fr][kk] = *(const bf16x8*)(Qp + (size_t)s * HDIM + (d0 ^ swb));
    }
  }

  f32x4 accO[2][8];
#pragma unroll
  for (int i = 0; i < 2; ++i)
#pragma unroll
    for (int j = 0; j < 8; ++j) {
      accO[i][j][0] = 0.f; accO[i][j][1] = 0.f; accO[i][j][2] = 0.f; accO[i][j][3] = 0.f;
    }
  float mrun[8], lrun[8];
#pragma unroll
  for (int i = 0; i < 8; ++i) { mrun[i] = -1e30f; lrun[i] = 0.f; }

  const char* KgBase = (const char*)Kp + (tid >> 4) * 256 + (tid & 15) * 16;
  const char* VgBase = (const char*)Vp + (size_t)(tid >> 3) * 4096 + (tid & 7) * 16;
  char* KldsW = (char*)Klds + w * 1024;
  char* VldsW = (char*)Vlds + w * 1024;

  const int ntiles = (q0 >> 6) + 2;
  const int qminw = q0 + w * 32;
  const int qmaxw = qminw + 31;

  for (int kt = 0; kt < ntiles; ++kt) {
    const int t0 = kt << 6;
    __syncthreads();
#pragma unroll
    for (int i = 0; i < 4; ++i)
      gl_lds16(KgBase + (size_t)t0 * 256 + i * 4096, KldsW + i * 4096);
#pragma unroll
    for (int i = 0; i < 4; ++i)
      gl_lds16(VgBase + t0 * 2 + (size_t)i * 131072, VldsW + i * 4096);
    __syncthreads();

    if (t0 <= qmaxw) {
      f32x4 sacc[2][4];
#pragma unroll
      for (int i = 0; i < 2; ++i)
#pragma unroll
        for (int j = 0; j < 4; ++j) {
          sacc[i][j][0] = 0.f; sacc[i][j][1] = 0.f; sacc[i][j][2] = 0.f; sacc[i][j][3] = 0.f;
        }
#pragma unroll
      for (int kk = 0; kk < 4; ++kk) {
        bf16x8 kf[4];
#pragma unroll
        for (int fn = 0; fn < 4; ++fn) {
          int t = fn * 16 + c;
          int d0 = kk * 32 + g * 8;
          kf[fn] = *(const bf16x8*)((const char*)Klds + t * 256 + ((d0 ^ ((t & 7) << 3)) << 1));
        }
#pragma unroll
        for (int fr = 0; fr < 2; ++fr)
#pragma unroll
          for (int fn = 0; fn < 4; ++fn)
            sacc[fr][fn] = mfma16(qf[fr][kk], kf[fn], sacc[fr][fn]);
      }
      if (t0 + 63 > qminw) {
#pragma unroll
        for (int fr = 0; fr < 2; ++fr)
#pragma unroll
          for (int fn = 0; fn < 4; ++fn)
#pragma unroll
            for (int r = 0; r < 4; ++r) {
              int q = qminw + fr * 16 + g * 4 + r;
              int t = t0 + fn * 16 + c;
              if (t > q) sacc[fr][fn][r] = -1e30f;
            }
      }
#pragma unroll
      for (int fr = 0; fr < 2; ++fr)
#pragma unroll
        for (int r = 0; r < 4; ++r) {
          float mx = fmaxf(fmaxf(sacc[fr][0][r], sacc[fr][1][r]),
                           fmaxf(sacc[fr][2][r], sacc[fr][3][r]));
          mx = fmaxf(mx, __shfl_xor(mx, 1));
          mx = fmaxf(mx, __shfl_xor(mx, 2));
          mx = fmaxf(mx, __shfl_xor(mx, 4));
          mx = fmaxf(mx, __shfl_xor(mx, 8));
          const int slot = fr * 4 + r;
          float mnew = fmaxf(mrun[slot], mx);
          float corr = expf(mrun[slot] - mnew);
          mrun[slot] = mnew;
#pragma unroll
          for (int fn = 0; fn < 8; ++fn) accO[fr][fn][r] *= corr;
          float rs = 0.f;
#pragma unroll
          for (int fn = 0; fn < 4; ++fn) {
            float e = expf(sacc[fr][fn][r] - mnew);
            sacc[fr][fn][r] = e;
            rs += e;
          }
          rs += __shfl_xor(rs, 1);
          rs += __shfl_xor(rs, 2);
          rs += __shfl_xor(rs, 4);
          rs += __shfl_xor(rs, 8);
          lrun[slot] = lrun[slot] * corr + rs;
          int prow = w * 32 + fr * 16 + g * 4 + r;
#pragma unroll
          for (int fn = 0; fn < 4; ++fn)
            Plds[prow * 72 + fn * 16 + c] = f2bf(sacc[fr][fn][r]);
        }
#pragma unroll
      for (int kk = 0; kk < 2; ++kk) {
        bf16x8 pa[2];
#pragma unroll
        for (int fr = 0; fr < 2; ++fr)
          pa[fr] = *(const bf16x8*)((const char*)Plds + (w * 32 + fr * 16 + c) * 144 + (kk * 32 + g * 8) * 2);
#pragma unroll
        for (int fn = 0; fn < 8; ++fn) {
          int d = fn * 16 + c;
          int tt = kk * 32 + g * 8;
          bf16x8 vb = *(const bf16x8*)((const char*)Vlds + d * 128 + ((tt ^ ((d & 7) << 3)) << 1));
#pragma unroll
          for (int fr = 0; fr < 2; ++fr)
            accO[fr][fn] = mfma16(pa[fr], vb, accO[fr][fn]);
        }
      }
    }
  }

  const int b = head >> 4, nh = head & 15;
#pragma unroll
  for (int fr = 0; fr < 2; ++fr)
#pragma unroll
    for (int r = 0; r < 4; ++r) {
      int q = q0 + w * 32 + fr * 16 + g * 4 + r;
      int m = q * 2 + b;
      float inv = 1.0f / lrun[fr * 4 + r];
      int swb = ((m >> 1) & 3) << 3;
#pragma unroll
      for (int fn = 0; fn < 8; ++fn) {
        int h = nh * 128 + fn * 16 + c;
        ctx[(size_t)m * HID + (h ^ swb)] = f2bf(accO[fr][fn][r] * inv);
      }
    }
}

extern "C" void kernel_launch(void* const* d_in, const int* in_sizes, int n_in,
                              void* d_out, int out_size, void* d_ws, size_t ws_size,
                              hipStream_t stream) {
  const float* hidden = (const float*)d_in[0];
  // d_in[1] = attention_mask: exactly causal tril/-1e9 -> computed in-kernel
  const float* Wqkv = (const float*)d_in[2];
  const float* bqkv = (const float*)d_in[3];
  const float* Wd   = (const float*)d_in[4];
  const float* bd   = (const float*)d_in[5];
  float* out = (float*)d_out;
  char* ws = (char*)d_ws;

  const size_t OFF_HID  = 0;          // 16 MiB (reused as ctx)
  const size_t OFF_WQKV = 16777216;   // 24 MiB
  const size_t OFF_WD   = 41943040;   // 8 MiB
  const size_t OFF_COS  = 50331648;   // 512 KiB
  const size_t OFF_SIN  = 50855936;   // 512 KiB
  const size_t OFF_Q    = 51380224;   // 16 MiB
  const size_t OFF_K    = 68157440;   // 16 MiB
  const size_t OFF_V    = 84934656;   // 16 MiB
  const size_t OFF_VT   = 101711872;  // 16 MiB -> total 118489088
  if (ws_size < 118489088) return;

  unsigned short* hidb  = (unsigned short*)(ws + OFF_HID);
  unsigned short* wqkvb = (unsigned short*)(ws + OFF_WQKV);
  unsigned short* wdb   = (unsigned short*)(ws + OFF_WD);
  float* cosT = (float*)(ws + OFF_COS);
  float* sinT = (float*)(ws + OFF_SIN);
  unsigned short* Qsb = (unsigned short*)(ws + OFF_Q);
  unsigned short* Ksb = (unsigned short*)(ws + OFF_K);
  unsigned short* Vpb = (unsigned short*)(ws + OFF_V);
  unsigned short* Vtb = (unsigned short*)(ws + OFF_VT);
  unsigned short* ctxb = hidb;  // reuse: hidden_bf16 dead after GEMM1

  conv_swz<<<8192, 256, 0, stream>>>(hidden, hidb);   // 4096x2048
  conv_swz<<<12288, 256, 0, stream>>>(Wqkv, wqkvb);   // 6144x2048
  conv_swz<<<4096, 256, 0, stream>>>(Wd, wdb);        // 2048x2048
  rope_cache_k<<<512, 256, 0, stream>>>(cosT, sinT);

  gemm_nt<0><<<dim3(48, 32), 256, 0, stream>>>(hidb, wqkvb, bqkv,
                                               Qsb, Ksb, Vpb, cosT, sinT, nullptr);
  transpose_v<<<1024, 256, 0, stream>>>(Vpb, Vtb);
  attn<<<512, 256, 0, stream>>>(Qsb, Ksb, Vtb, ctxb);
  gemm_nt<1><<<dim3(16, 32), 256, 0, stream>>>(ctxb, wdb, bd,
                                               nullptr, nullptr, nullptr, nullptr, nullptr, out);
}

// Round 2
// 341.784 us; speedup vs baseline: 1.0144x; 1.0144x over previous
//
#include <hip/hip_runtime.h>

#define SEQ   2048
#define BATCH 2
#define HID   2048
#define NHEAD 16
#define HDIM  128
#define MTOT  4096
#define KDIM  2048

typedef __attribute__((ext_vector_type(8))) short  bf16x8;
typedef __attribute__((ext_vector_type(4))) float  f32x4;
typedef __attribute__((ext_vector_type(4))) unsigned short u16x4;
typedef __attribute__((ext_vector_type(8))) unsigned short u16x8;

__device__ __forceinline__ unsigned short f2bf(float x) {
  unsigned u = __float_as_uint(x);
  u += 0x7fffu + ((u >> 16) & 1u);
  return (unsigned short)(u >> 16);
}

__device__ __forceinline__ void gl_lds16(const void* g, void* l) {
  __builtin_amdgcn_global_load_lds(
      (__attribute__((address_space(1))) void*)g,
      (__attribute__((address_space(3))) void*)l, 16, 0, 0);
}

__device__ __forceinline__ f32x4 mfma16(bf16x8 a, bf16x8 b, f32x4 c) {
  return __builtin_amdgcn_mfma_f32_16x16x32_bf16(a, b, c, 0, 0, 0);
}

// fp32 -> bf16 with K-granule swizzle (rows of length 2048):
// element (r,k) stored at r*2048 + (k ^ (((r>>1)&3)<<3))
__global__ __launch_bounds__(256, 8)
void conv_swz(const float* __restrict__ src, unsigned short* __restrict__ dst) {
  int i = blockIdx.x * 256 + threadIdx.x;
  int base = i << 2;
  int r = base >> 11, k = base & 2047;
  f32x4 v = *(const f32x4*)(src + base);
  int kp = k ^ (((r >> 1) & 3) << 3);
  u16x4 o;
  o[0] = f2bf(v[0]); o[1] = f2bf(v[1]); o[2] = f2bf(v[2]); o[3] = f2bf(v[3]);
  *(u16x4*)(dst + (size_t)r * 2048 + kp) = o;
}

__global__ __launch_bounds__(256, 8)
void rope_cache_k(float* __restrict__ cosT, float* __restrict__ sinT) {
  int idx = blockIdx.x * 256 + threadIdx.x;   // 2048*64
  int s = idx >> 6, i = idx & 63;
  float inv = powf(1e-4f, (float)i * (1.0f / 64.0f));
  float a = (float)s * inv;
  cosT[idx] = cosf(a);
  sinT[idx] = sinf(a);
}

// ---------------------------------------------------------------------------
// 256x256 8-phase NT GEMM (BK=64, 8 waves = 4M x 2N, 128KiB LDS, counted vmcnt)
// C[m][n] = sum_k A[m][k]*Bt[n][k], K=2048. A/Bt bf16 with conv_swz swizzle.
// Per wave: 64 rows x 128 cols = 4 M-frags x 8 N-frags of 16x16.
// LDS: A slots [buf][khalf][256][32] at 0..64K, B same at 64K..128K.
// Per K-tile group of 4 phases (nh,ks)=(0,0),(1,0),(0,1),(1,1):
//   reads:  gp1: A-k0 + B-k0(nf0-3); gp2: B-k0(nf4-7); gp3: A-k1 + B-k1(nf0-3); gp4: B-k1(nf4-7)
//   issues: gp1: B-k1(t+1)->buf^1;  gp2: A-k0(t+2)->buf; gp3: B-k0(t+2)->buf; gp4: A-k1(t+2)->buf
//   wait:   vmcnt(6) at gp4 (3 half-tiles in flight), vmcnt(0) at the tail.
// ---------------------------------------------------------------------------
template<int EPI>
__global__ __launch_bounds__(512, 2)
void gemm8p(const unsigned short* __restrict__ A,
            const unsigned short* __restrict__ Bt,
            const float* __restrict__ bias,
            unsigned short* __restrict__ Qs,
            unsigned short* __restrict__ Ks,
            unsigned short* __restrict__ Vp,
            const float* __restrict__ cosT,
            const float* __restrict__ sinT,
            float* __restrict__ Cout)
{
  __shared__ alignas(16) short lds[65536];   // 128 KiB
  const int tid = threadIdx.x;
  const int wid = tid >> 6, lane = tid & 63, g = lane >> 4, c = lane & 15;
  const int wr = wid >> 1, wc = wid & 1;
  const int m0 = blockIdx.y << 8, n0 = blockIdx.x << 8;

  char* ldsb = (char*)lds;
  const int slotg = (g ^ ((c >> 1) & 3)) << 4;
  const char* ldsAr = ldsb + ((wr * 64 + c) * 64 + slotg);
  const char* ldsBr = ldsb + 65536 + ((wc * 128 + c) * 64 + slotg);

  const char* gA = (const char*)A  + (size_t)(m0 + (tid >> 2)) * 4096 + (tid & 3) * 16;
  const char* gB = (const char*)Bt + (size_t)(n0 + (tid >> 2)) * 4096 + (tid & 3) * 16;
  char* lA = ldsb + tid * 16;
  char* lB = ldsb + 65536 + tid * 16;

#define STG_A(T, KS, BUF) do { int _ko = (T) * 128 + (KS) * 64;            \
    gl_lds16(gA + _ko,          lA + ((BUF) * 2 + (KS)) * 16384);          \
    gl_lds16(gA + _ko + 524288, lA + ((BUF) * 2 + (KS)) * 16384 + 8192); } while (0)
#define STG_B(T, KS, BUF) do { int _ko = (T) * 128 + (KS) * 64;            \
    gl_lds16(gB + _ko,          lB + ((BUF) * 2 + (KS)) * 16384);          \
    gl_lds16(gB + _ko + 524288, lB + ((BUF) * 2 + (KS)) * 16384 + 8192); } while (0)

  f32x4 acc[4][8];
#pragma unroll
  for (int i = 0; i < 4; ++i)
#pragma unroll
    for (int j = 0; j < 8; ++j) {
      acc[i][j][0] = 0.f; acc[i][j][1] = 0.f; acc[i][j][2] = 0.f; acc[i][j][3] = 0.f;
    }

  bf16x8 a[4], b[4];

#define LDA(KS, BUF) do { _Pragma("unroll")                                 \
    for (int mf = 0; mf < 4; ++mf)                                          \
      a[mf] = *(const bf16x8*)(ldsAr + ((BUF) * 2 + (KS)) * 16384 + mf * 1024); } while (0)
#define LDB(KS, NH, BUF) do { _Pragma("unroll")                             \
    for (int nf = 0; nf < 4; ++nf)                                          \
      b[nf] = *(const bf16x8*)(ldsBr + ((BUF) * 2 + (KS)) * 16384 + ((NH) * 4 + nf) * 1024); } while (0)

#define PHASE(NH, KS, BUF, STAGE, VMW) do {                                 \
    if ((NH) == 0) { LDA(KS, BUF); }                                        \
    LDB(KS, NH, BUF);                                                       \
    STAGE;                                                                  \
    __builtin_amdgcn_s_barrier();                                           \
    asm volatile("s_waitcnt lgkmcnt(0)" ::: "memory");                      \
    __builtin_amdgcn_s_setprio(1);                                          \
    _Pragma("unroll")                                                       \
    for (int mf = 0; mf < 4; ++mf)                                          \
      _Pragma("unroll")                                                     \
      for (int nf = 0; nf < 4; ++nf)                                        \
        acc[mf][(NH) * 4 + nf] = mfma16(a[mf], b[nf], acc[mf][(NH) * 4 + nf]); \
    __builtin_amdgcn_s_setprio(0);                                          \
    VMW;                                                                    \
    __builtin_amdgcn_s_barrier();                                           \
  } while (0)

  const int NT = KDIM / 64;   // 32

  // Prologue: tile0 (4 half-tiles) + tile1 (3) = 7; wait so tile0 landed.
  STG_A(0, 0, 0); STG_B(0, 0, 0); STG_A(0, 1, 0); STG_B(0, 1, 0);
  STG_A(1, 0, 1); STG_B(1, 0, 1); STG_A(1, 1, 1);
  asm volatile("s_waitcnt vmcnt(6)" ::: "memory");
  __builtin_amdgcn_s_barrier();

#define GROUP(T, BUF) do {                                                  \
    PHASE(0, 0, BUF, { if ((T) + 1 < NT) STG_B((T) + 1, 1, (BUF) ^ 1); }, ((void)0)); \
    PHASE(1, 0, BUF, { if ((T) + 2 < NT) STG_A((T) + 2, 0, (BUF)); },  ((void)0));    \
    PHASE(0, 1, BUF, { if ((T) + 2 < NT) STG_B((T) + 2, 0, (BUF)); },  ((void)0));    \
    PHASE(1, 1, BUF, { if ((T) + 2 < NT) STG_A((T) + 2, 1, (BUF)); },               \
      { if ((T) + 2 < NT) { asm volatile("s_waitcnt vmcnt(6)" ::: "memory"); }      \
        else              { asm volatile("s_waitcnt vmcnt(0)" ::: "memory"); } });  \
  } while (0)

  for (int t = 0; t < NT; t += 2) {
    GROUP(t, 0);
    GROUP(t + 1, 1);
  }

  // ---------------- epilogue ----------------
  if (EPI == 0) {
    const int pbase = n0 + wc * 128;        // 128-aligned panel
    const int nh = pbase / 384;
    const int type = (pbase % 384) >> 7;    // 0=q, 1=k, 2=v
    if (type < 2) {
      unsigned short* dst = (type == 0) ? Qs : Ks;
      const float qsc = (type == 0) ? 0.08838834764831845f : 1.0f;
#pragma unroll
      for (int mf = 0; mf < 4; ++mf)
#pragma unroll
        for (int rr = 0; rr < 4; ++rr) {
          int m = m0 + wr * 64 + mf * 16 + g * 4 + rr;
          int s = m >> 1, bb = m & 1;
          size_t plane = (size_t)(bb * NHEAD + nh) * (SEQ * HDIM);
          int swb = (s & 7) << 3;
#pragma unroll
          for (int nf = 0; nf < 4; ++nf) {
            int dl = nf * 16 + c;
            float xl = acc[mf][nf][rr]     + bias[pbase + dl];
            float xr = acc[mf][nf + 4][rr] + bias[pbase + 64 + dl];
            float co = cosT[s * 64 + dl], si = sinT[s * 64 + dl];
            dst[plane + (size_t)s * HDIM + (dl ^ swb)]        = f2bf((co * xl - si * xr) * qsc);
            dst[plane + (size_t)s * HDIM + ((dl + 64) ^ swb)] = f2bf((si * xl + co * xr) * qsc);
          }
        }
    } else {
#pragma unroll
      for (int mf = 0; mf < 4; ++mf)
#pragma unroll
        for (int rr = 0; rr < 4; ++rr) {
          int m = m0 + wr * 64 + mf * 16 + g * 4 + rr;
          int s = m >> 1, bb = m & 1;
          size_t plane = (size_t)(bb * NHEAD + nh) * (SEQ * HDIM);
#pragma unroll
          for (int nf = 0; nf < 8; ++nf) {
            int d = nf * 16 + c;
            Vp[plane + (size_t)s * HDIM + d] = f2bf(acc[mf][nf][rr] + bias[pbase + d]);
          }
        }
    }
  } else {
#pragma unroll
    for (int mf = 0; mf < 4; ++mf)
#pragma unroll
      for (int rr = 0; rr < 4; ++rr) {
        int m = m0 + wr * 64 + mf * 16 + g * 4 + rr;
#pragma unroll
        for (int nf = 0; nf < 8; ++nf) {
          int n = n0 + wc * 128 + nf * 16 + c;
          Cout[(size_t)m * HID + n] = acc[mf][nf][rr] + bias[n];
        }
      }
  }
#undef GROUP
#undef PHASE
#undef LDA
#undef LDB
#undef STG_A
#undef STG_B
}

// V [plane][t][d] -> Vt [plane][d][t], t-granule swizzled: (t ^ ((d&7)<<3))
__global__ __launch_bounds__(256, 4)
void transpose_v(const unsigned short* __restrict__ Vp, unsigned short* __restrict__ Vt) {
  __shared__ alignas(16) unsigned short T[64 * 136];
  const int plane = blockIdx.x >> 5;
  const int t0 = (blockIdx.x & 31) << 6;
  const size_t pbase = (size_t)plane * (SEQ * HDIM);
  const int tid = threadIdx.x;
  {
    int t = tid >> 2, d0 = (tid & 3) << 5;
    const unsigned short* src = Vp + pbase + (size_t)(t0 + t) * HDIM + d0;
#pragma unroll
    for (int j = 0; j < 4; ++j) {
      u16x8 v = *(const u16x8*)(src + j * 8);
      *(u16x8*)(&T[t * 136 + d0 + j * 8]) = v;
    }
  }
  __syncthreads();
  {
    int d = tid >> 1, half = tid & 1;
    unsigned short* dstp = Vt + pbase + (size_t)d * SEQ;
    int swb = (d & 7) << 3;
#pragma unroll
    for (int gg = 0; gg < 4; ++gg) {
      u16x8 v;
#pragma unroll
      for (int e = 0; e < 8; ++e)
        v[e] = T[(half * 32 + gg * 8 + e) * 136 + d];
      int tloc = half * 32 + gg * 8;
      *(u16x8*)(dstp + ((t0 + tloc) ^ swb)) = v;
    }
  }
}

// Flash attention. 512 blocks: blockIdx.x = (15-qb)*32 + head (heavy first).
__global__ __launch_bounds__(256, 2)
void attn(const unsigned short* __restrict__ Qs,
          const unsigned short* __restrict__ Ks,
          const unsigned short* __restrict__ Vt,
          unsigned short* __restrict__ ctx)
{
  __shared__ alignas(16) unsigned short Klds[64 * 128];
  __shared__ alignas(16) unsigned short Vlds[128 * 64];
  __shared__ alignas(16) unsigned short Plds[128 * 72];
  const int tid = threadIdx.x;
  const int w = tid >> 6, lane = tid & 63, g = lane >> 4, c = lane & 15;
  const int head = blockIdx.x & 31;
  const int qb = 15 - (blockIdx.x >> 5);
  const int q0 = qb << 7;
  const size_t plane = (size_t)head * (SEQ * HDIM);
  const unsigned short* Qp = Qs + plane;
  const unsigned short* Kp = Ks + plane;
  const unsigned short* Vp = Vt + plane;

  bf16x8 qf[2][4];
#pragma unroll
  for (int fr = 0; fr < 2; ++fr) {
    int s = q0 + w * 32 + fr * 16 + c;
    int swb = (s & 7) << 3;
#pragma unroll
    for (int kk = 0; kk < 4; ++kk) {
      int d0 = kk * 32 + g * 8;
      qf[fr][kk] = *(const bf16x8*)(Qp + (size_t)s * HDIM + (d0 ^ swb));
    }
  }

  f32x4 accO[2][8];
#pragma unroll
  for (int i = 0; i < 2; ++i)
#pragma unroll
    for (int j = 0; j < 8; ++j) {
      accO[i][j][0] = 0.f; accO[i][j][1] = 0.f; accO[i][j][2] = 0.f; accO[i][j][3] = 0.f;
    }
  float mrun[8], lrun[8];
#pragma unroll
  for (int i = 0; i < 8; ++i) { mrun[i] = -1e30f; lrun[i] = 0.f; }

  const char* KgBase = (const char*)Kp + (tid >> 4) * 256 + (tid & 15) * 16;
  const char* VgBase = (const char*)Vp + (size_t)(tid >> 3) * 4096 + (tid & 7) * 16;
  char* KldsW = (char*)Klds + w * 1024;
  char* VldsW = (char*)Vlds + w * 1024;

  const int ntiles = (q0 >> 6) + 2;
  const int qminw = q0 + w * 32;
  const int qmaxw = qminw + 31;

  for (int kt = 0; kt < ntiles; ++kt) {
    const int t0 = kt << 6;
    __syncthreads();
#pragma unroll
    for (int i = 0; i < 4; ++i)
      gl_lds16(KgBase + (size_t)t0 * 256 + i * 4096, KldsW + i * 4096);
#pragma unroll
    for (int i = 0; i < 4; ++i)
      gl_lds16(VgBase + t0 * 2 + (size_t)i * 131072, VldsW + i * 4096);
    __syncthreads();

    if (t0 <= qmaxw) {
      f32x4 sacc[2][4];
#pragma unroll
      for (int i = 0; i < 2; ++i)
#pragma unroll
        for (int j = 0; j < 4; ++j) {
          sacc[i][j][0] = 0.f; sacc[i][j][1] = 0.f; sacc[i][j][2] = 0.f; sacc[i][j][3] = 0.f;
        }
#pragma unroll
      for (int kk = 0; kk < 4; ++kk) {
        bf16x8 kf[4];
#pragma unroll
        for (int fn = 0; fn < 4; ++fn) {
          int t = fn * 16 + c;
          int d0 = kk * 32 + g * 8;
          kf[fn] = *(const bf16x8*)((const char*)Klds + t * 256 + ((d0 ^ ((t & 7) << 3)) << 1));
        }
#pragma unroll
        for (int fr = 0; fr < 2; ++fr)
#pragma unroll
          for (int fn = 0; fn < 4; ++fn)
            sacc[fr][fn] = mfma16(qf[fr][kk], kf[fn], sacc[fr][fn]);
      }
      if (t0 + 63 > qminw) {
#pragma unroll
        for (int fr = 0; fr < 2; ++fr)
#pragma unroll
          for (int fn = 0; fn < 4; ++fn)
#pragma unroll
            for (int r = 0; r < 4; ++r) {
              int q = qminw + fr * 16 + g * 4 + r;
              int t = t0 + fn * 16 + c;
              if (t > q) sacc[fr][fn][r] = -1e30f;
            }
      }
#pragma unroll
      for (int fr = 0; fr < 2; ++fr)
#pragma unroll
        for (int r = 0; r < 4; ++r) {
          float mx = fmaxf(fmaxf(sacc[fr][0][r], sacc[fr][1][r]),
                           fmaxf(sacc[fr][2][r], sacc[fr][3][r]));
          mx = fmaxf(mx, __shfl_xor(mx, 1));
          mx = fmaxf(mx, __shfl_xor(mx, 2));
          mx = fmaxf(mx, __shfl_xor(mx, 4));
          mx = fmaxf(mx, __shfl_xor(mx, 8));
          const int slot = fr * 4 + r;
          float mnew = fmaxf(mrun[slot], mx);
          float corr = expf(mrun[slot] - mnew);
          mrun[slot] = mnew;
#pragma unroll
          for (int fn = 0; fn < 8; ++fn) accO[fr][fn][r] *= corr;
          float rs = 0.f;
#pragma unroll
          for (int fn = 0; fn < 4; ++fn) {
            float e = expf(sacc[fr][fn][r] - mnew);
            sacc[fr][fn][r] = e;
            rs += e;
          }
          rs += __shfl_xor(rs, 1);
          rs += __shfl_xor(rs, 2);
          rs += __shfl_xor(rs, 4);
          rs += __shfl_xor(rs, 8);
          lrun[slot] = lrun[slot] * corr + rs;
          int prow = w * 32 + fr * 16 + g * 4 + r;
#pragma unroll
          for (int fn = 0; fn < 4; ++fn)
            Plds[prow * 72 + fn * 16 + c] = f2bf(sacc[fr][fn][r]);
        }
#pragma unroll
      for (int kk = 0; kk < 2; ++kk) {
        bf16x8 pa[2];
#pragma unroll
        for (int fr = 0; fr < 2; ++fr)
          pa[fr] = *(const bf16x8*)((const char*)Plds + (w * 32 + fr * 16 + c) * 144 + (kk * 32 + g * 8) * 2);
#pragma unroll
        for (int fn = 0; fn < 8; ++fn) {
          int d = fn * 16 + c;
          int tt = kk * 32 + g * 8;
          bf16x8 vb = *(const bf16x8*)((const char*)Vlds + d * 128 + ((tt ^ ((d & 7) << 3)) << 1));
#pragma unroll
          for (int fr = 0; fr < 2; ++fr)
            accO[fr][fn] = mfma16(pa[fr], vb, accO[fr][fn]);
        }
      }
    }
  }

  const int b = head >> 4, nh = head & 15;
#pragma unroll
  for (int fr = 0; fr < 2; ++fr)
#pragma unroll
    for (int r = 0; r < 4; ++r) {
      int q = q0 + w * 32 + fr * 16 + g * 4 + r;
      int m = q * 2 + b;
      float inv = 1.0f / lrun[fr * 4 + r];
      int swb = ((m >> 1) & 3) << 3;
#pragma unroll
      for (int fn = 0; fn < 8; ++fn) {
        int h = nh * 128 + fn * 16 + c;
        ctx[(size_t)m * HID + (h ^ swb)] = f2bf(accO[fr][fn][r] * inv);
      }
    }
}

extern "C" void kernel_launch(void* const* d_in, const int* in_sizes, int n_in,
                              void* d_out, int out_size, void* d_ws, size_t ws_size,
                              hipStream_t stream) {
  const float* hidden = (const float*)d_in[0];
  // d_in[1] = attention_mask: exactly causal tril/-1e9 -> computed in-kernel
  const float* Wqkv = (const float*)d_in[2];
  const float* bqkv = (const float*)d_in[3];
  const float* Wd   = (const float*)d_in[4];
  const float* bd   = (const float*)d_in[5];
  float* out = (float*)d_out;
  char* ws = (char*)d_ws;

  const size_t OFF_HID  = 0;          // 16 MiB (reused as ctx)
  const size_t OFF_WQKV = 16777216;   // 24 MiB
  const size_t OFF_WD   = 41943040;   // 8 MiB
  const size_t OFF_COS  = 50331648;   // 512 KiB
  const size_t OFF_SIN  = 50855936;   // 512 KiB
  const size_t OFF_Q    = 51380224;   // 16 MiB
  const size_t OFF_K    = 68157440;   // 16 MiB
  const size_t OFF_V    = 84934656;   // 16 MiB
  const size_t OFF_VT   = 101711872;  // 16 MiB -> total 118489088
  if (ws_size < 118489088) return;

  unsigned short* hidb  = (unsigned short*)(ws + OFF_HID);
  unsigned short* wqkvb = (unsigned short*)(ws + OFF_WQKV);
  unsigned short* wdb   = (unsigned short*)(ws + OFF_WD);
  float* cosT = (float*)(ws + OFF_COS);
  float* sinT = (float*)(ws + OFF_SIN);
  unsigned short* Qsb = (unsigned short*)(ws + OFF_Q);
  unsigned short* Ksb = (unsigned short*)(ws + OFF_K);
  unsigned short* Vpb = (unsigned short*)(ws + OFF_V);
  unsigned short* Vtb = (unsigned short*)(ws + OFF_VT);
  unsigned short* ctxb = hidb;  // reuse: hidden_bf16 dead after GEMM1

  conv_swz<<<8192, 256, 0, stream>>>(hidden, hidb);   // 4096x2048
  conv_swz<<<12288, 256, 0, stream>>>(Wqkv, wqkvb);   // 6144x2048
  conv_swz<<<4096, 256, 0, stream>>>(Wd, wdb);        // 2048x2048
  rope_cache_k<<<512, 256, 0, stream>>>(cosT, sinT);

  gemm8p<0><<<dim3(24, 16), 512, 0, stream>>>(hidb, wqkvb, bqkv,
                                              Qsb, Ksb, Vpb, cosT, sinT, nullptr);
  transpose_v<<<1024, 256, 0, stream>>>(Vpb, Vtb);
  attn<<<512, 256, 0, stream>>>(Qsb, Ksb, Vtb, ctxb);
  gemm8p<1><<<dim3(8, 16), 512, 0, stream>>>(ctxb, wdb, bd,
                                             nullptr, nullptr, nullptr, nullptr, nullptr, out);
}

// Round 3
// 280.313 us; speedup vs baseline: 1.2368x; 1.2193x over previous
//
#include <hip/hip_runtime.h>

#define SEQ   2048
#define BATCH 2
#define HID   2048
#define NHEAD 16
#define HDIM  128
#define MTOT  4096
#define KDIM  2048

typedef __attribute__((ext_vector_type(8))) short  bf16x8;
typedef __attribute__((ext_vector_type(4))) float  f32x4;
typedef __attribute__((ext_vector_type(4))) unsigned short u16x4;
typedef __attribute__((ext_vector_type(8))) unsigned short u16x8;

__device__ __forceinline__ unsigned short f2bf(float x) {
  unsigned u = __float_as_uint(x);
  u += 0x7fffu + ((u >> 16) & 1u);
  return (unsigned short)(u >> 16);
}

__device__ __forceinline__ float fexp2(float x) {
  float r;
  asm("v_exp_f32 %0, %1" : "=v"(r) : "v"(x));
  return r;
}

__device__ __forceinline__ void gl_lds16(const void* g, void* l) {
  __builtin_amdgcn_global_load_lds(
      (__attribute__((address_space(1))) void*)g,
      (__attribute__((address_space(3))) void*)l, 16, 0, 0);
}

__device__ __forceinline__ f32x4 mfma16(bf16x8 a, bf16x8 b, f32x4 c) {
  return __builtin_amdgcn_mfma_f32_16x16x32_bf16(a, b, c, 0, 0, 0);
}

// fp32 -> bf16 with K-granule swizzle (rows of length 2048):
// element (r,k) stored at r*2048 + (k ^ (((r>>1)&3)<<3))
__global__ __launch_bounds__(256, 8)
void conv_swz(const float* __restrict__ src, unsigned short* __restrict__ dst) {
  int i = blockIdx.x * 256 + threadIdx.x;
  int base = i << 2;
  int r = base >> 11, k = base & 2047;
  f32x4 v = *(const f32x4*)(src + base);
  int kp = k ^ (((r >> 1) & 3) << 3);
  u16x4 o;
  o[0] = f2bf(v[0]); o[1] = f2bf(v[1]); o[2] = f2bf(v[2]); o[3] = f2bf(v[3]);
  *(u16x4*)(dst + (size_t)r * 2048 + kp) = o;
}

__global__ __launch_bounds__(256, 8)
void rope_cache_k(float* __restrict__ cosT, float* __restrict__ sinT) {
  int idx = blockIdx.x * 256 + threadIdx.x;   // 2048*64
  int s = idx >> 6, i = idx & 63;
  float inv = powf(1e-4f, (float)i * (1.0f / 64.0f));
  float a = (float)s * inv;
  cosT[idx] = cosf(a);
  sinT[idx] = sinf(a);
}

// ---------------------------------------------------------------------------
// 256x256 8-phase NT GEMM (unchanged from round 2)
// ---------------------------------------------------------------------------
template<int EPI>
__global__ __launch_bounds__(512, 2)
void gemm8p(const unsigned short* __restrict__ A,
            const unsigned short* __restrict__ Bt,
            const float* __restrict__ bias,
            unsigned short* __restrict__ Qs,
            unsigned short* __restrict__ Ks,
            unsigned short* __restrict__ Vp,
            const float* __restrict__ cosT,
            const float* __restrict__ sinT,
            float* __restrict__ Cout)
{
  __shared__ alignas(16) short lds[65536];   // 128 KiB
  const int tid = threadIdx.x;
  const int wid = tid >> 6, lane = tid & 63, g = lane >> 4, c = lane & 15;
  const int wr = wid >> 1, wc = wid & 1;
  const int m0 = blockIdx.y << 8, n0 = blockIdx.x << 8;

  char* ldsb = (char*)lds;
  const int slotg = (g ^ ((c >> 1) & 3)) << 4;
  const char* ldsAr = ldsb + ((wr * 64 + c) * 64 + slotg);
  const char* ldsBr = ldsb + 65536 + ((wc * 128 + c) * 64 + slotg);

  const char* gA = (const char*)A  + (size_t)(m0 + (tid >> 2)) * 4096 + (tid & 3) * 16;
  const char* gB = (const char*)Bt + (size_t)(n0 + (tid >> 2)) * 4096 + (tid & 3) * 16;
  char* lA = ldsb + tid * 16;
  char* lB = ldsb + 65536 + tid * 16;

#define STG_A(T, KS, BUF) do { int _ko = (T) * 128 + (KS) * 64;            \
    gl_lds16(gA + _ko,          lA + ((BUF) * 2 + (KS)) * 16384);          \
    gl_lds16(gA + _ko + 524288, lA + ((BUF) * 2 + (KS)) * 16384 + 8192); } while (0)
#define STG_B(T, KS, BUF) do { int _ko = (T) * 128 + (KS) * 64;            \
    gl_lds16(gB + _ko,          lB + ((BUF) * 2 + (KS)) * 16384);          \
    gl_lds16(gB + _ko + 524288, lB + ((BUF) * 2 + (KS)) * 16384 + 8192); } while (0)

  f32x4 acc[4][8];
#pragma unroll
  for (int i = 0; i < 4; ++i)
#pragma unroll
    for (int j = 0; j < 8; ++j) {
      acc[i][j][0] = 0.f; acc[i][j][1] = 0.f; acc[i][j][2] = 0.f; acc[i][j][3] = 0.f;
    }

  bf16x8 a[4], b[4];

#define LDA(KS, BUF) do { _Pragma("unroll")                                 \
    for (int mf = 0; mf < 4; ++mf)                                          \
      a[mf] = *(const bf16x8*)(ldsAr + ((BUF) * 2 + (KS)) * 16384 + mf * 1024); } while (0)
#define LDB(KS, NH, BUF) do { _Pragma("unroll")                             \
    for (int nf = 0; nf < 4; ++nf)                                          \
      b[nf] = *(const bf16x8*)(ldsBr + ((BUF) * 2 + (KS)) * 16384 + ((NH) * 4 + nf) * 1024); } while (0)

#define PHASE(NH, KS, BUF, STAGE, VMW) do {                                 \
    if ((NH) == 0) { LDA(KS, BUF); }                                        \
    LDB(KS, NH, BUF);                                                       \
    STAGE;                                                                  \
    __builtin_amdgcn_s_barrier();                                           \
    asm volatile("s_waitcnt lgkmcnt(0)" ::: "memory");                      \
    __builtin_amdgcn_s_setprio(1);                                          \
    _Pragma("unroll")                                                       \
    for (int mf = 0; mf < 4; ++mf)                                          \
      _Pragma("unroll")                                                     \
      for (int nf = 0; nf < 4; ++nf)                                        \
        acc[mf][(NH) * 4 + nf] = mfma16(a[mf], b[nf], acc[mf][(NH) * 4 + nf]); \
    __builtin_amdgcn_s_setprio(0);                                          \
    VMW;                                                                    \
    __builtin_amdgcn_s_barrier();                                           \
  } while (0)

  const int NT = KDIM / 64;   // 32

  STG_A(0, 0, 0); STG_B(0, 0, 0); STG_A(0, 1, 0); STG_B(0, 1, 0);
  STG_A(1, 0, 1); STG_B(1, 0, 1); STG_A(1, 1, 1);
  asm volatile("s_waitcnt vmcnt(6)" ::: "memory");
  __builtin_amdgcn_s_barrier();

#define GROUP(T, BUF) do {                                                  \
    PHASE(0, 0, BUF, { if ((T) + 1 < NT) STG_B((T) + 1, 1, (BUF) ^ 1); }, ((void)0)); \
    PHASE(1, 0, BUF, { if ((T) + 2 < NT) STG_A((T) + 2, 0, (BUF)); },  ((void)0));    \
    PHASE(0, 1, BUF, { if ((T) + 2 < NT) STG_B((T) + 2, 0, (BUF)); },  ((void)0));    \
    PHASE(1, 1, BUF, { if ((T) + 2 < NT) STG_A((T) + 2, 1, (BUF)); },               \
      { if ((T) + 2 < NT) { asm volatile("s_waitcnt vmcnt(6)" ::: "memory"); }      \
        else              { asm volatile("s_waitcnt vmcnt(0)" ::: "memory"); } });  \
  } while (0)

  for (int t = 0; t < NT; t += 2) {
    GROUP(t, 0);
    GROUP(t + 1, 1);
  }

  if (EPI == 0) {
    const int pbase = n0 + wc * 128;
    const int nh = pbase / 384;
    const int type = (pbase % 384) >> 7;
    if (type < 2) {
      unsigned short* dst = (type == 0) ? Qs : Ks;
      // log2(e)/sqrt(128) folded into Q so attention softmax runs in exp2 domain
      const float qsc = (type == 0) ? 0.08838834764831845f * 1.4426950408889634f : 1.0f;
#pragma unroll
      for (int mf = 0; mf < 4; ++mf)
#pragma unroll
        for (int rr = 0; rr < 4; ++rr) {
          int m = m0 + wr * 64 + mf * 16 + g * 4 + rr;
          int s = m >> 1, bb = m & 1;
          size_t plane = (size_t)(bb * NHEAD + nh) * (SEQ * HDIM);
          int swb = (s & 7) << 3;
#pragma unroll
          for (int nf = 0; nf < 4; ++nf) {
            int dl = nf * 16 + c;
            float xl = acc[mf][nf][rr]     + bias[pbase + dl];
            float xr = acc[mf][nf + 4][rr] + bias[pbase + 64 + dl];
            float co = cosT[s * 64 + dl], si = sinT[s * 64 + dl];
            dst[plane + (size_t)s * HDIM + (dl ^ swb)]        = f2bf((co * xl - si * xr) * qsc);
            dst[plane + (size_t)s * HDIM + ((dl + 64) ^ swb)] = f2bf((si * xl + co * xr) * qsc);
          }
        }
    } else {
#pragma unroll
      for (int mf = 0; mf < 4; ++mf)
#pragma unroll
        for (int rr = 0; rr < 4; ++rr) {
          int m = m0 + wr * 64 + mf * 16 + g * 4 + rr;
          int s = m >> 1, bb = m & 1;
          size_t plane = (size_t)(bb * NHEAD + nh) * (SEQ * HDIM);
#pragma unroll
          for (int nf = 0; nf < 8; ++nf) {
            int d = nf * 16 + c;
            Vp[plane + (size_t)s * HDIM + d] = f2bf(acc[mf][nf][rr] + bias[pbase + d]);
          }
        }
    }
  } else {
#pragma unroll
    for (int mf = 0; mf < 4; ++mf)
#pragma unroll
      for (int rr = 0; rr < 4; ++rr) {
        int m = m0 + wr * 64 + mf * 16 + g * 4 + rr;
#pragma unroll
        for (int nf = 0; nf < 8; ++nf) {
          int n = n0 + wc * 128 + nf * 16 + c;
          Cout[(size_t)m * HID + n] = acc[mf][nf][rr] + bias[n];
        }
      }
  }
#undef GROUP
#undef PHASE
#undef LDA
#undef LDB
#undef STG_A
#undef STG_B
}

// V [plane][t][d] -> Vt [plane][d][t], t-granule swizzled: (t ^ ((d&7)<<3))
__global__ __launch_bounds__(256, 4)
void transpose_v(const unsigned short* __restrict__ Vp, unsigned short* __restrict__ Vt) {
  __shared__ alignas(16) unsigned short T[64 * 136];
  const int plane = blockIdx.x >> 5;
  const int t0 = (blockIdx.x & 31) << 6;
  const size_t pbase = (size_t)plane * (SEQ * HDIM);
  const int tid = threadIdx.x;
  {
    int t = tid >> 2, d0 = (tid & 3) << 5;
    const unsigned short* src = Vp + pbase + (size_t)(t0 + t) * HDIM + d0;
#pragma unroll
    for (int j = 0; j < 4; ++j) {
      u16x8 v = *(const u16x8*)(src + j * 8);
      *(u16x8*)(&T[t * 136 + d0 + j * 8]) = v;
    }
  }
  __syncthreads();
  {
    int d = tid >> 1, half = tid & 1;
    unsigned short* dstp = Vt + pbase + (size_t)d * SEQ;
    int swb = (d & 7) << 3;
#pragma unroll
    for (int gg = 0; gg < 4; ++gg) {
      u16x8 v;
#pragma unroll
      for (int e = 0; e < 8; ++e)
        v[e] = T[(half * 32 + gg * 8 + e) * 136 + d];
      int tloc = half * 32 + gg * 8;
      *(u16x8*)(dstp + ((t0 + tloc) ^ swb)) = v;
    }
  }
}

// ---------------------------------------------------------------------------
// Flash attention, swapped-QK^T + async K double-buffer + counted vmcnt.
// 512 blocks: bid<256 -> heavy qb = 15-(bid>>5); bid>=256 -> light qb = (bid>>5)-8.
// CU-resident pairs (heavy,light) sum to uniform work.
// Scores arrive in exp2 domain (log2e folded into Q scale by GEMM epilogue).
// ---------------------------------------------------------------------------
__global__ __launch_bounds__(256, 2)
void attn(const unsigned short* __restrict__ Qs,
          const unsigned short* __restrict__ Ks,
          const unsigned short* __restrict__ Vt,
          unsigned short* __restrict__ ctx)
{
  __shared__ alignas(16) unsigned short Klds[2][64 * 128];
  __shared__ alignas(16) unsigned short Vlds[128 * 64];
  __shared__ alignas(16) unsigned short Plds[128 * 72];
  const int tid = threadIdx.x;
  const int w = tid >> 6, lane = tid & 63, g = lane >> 4, c = lane & 15;
  const int bid = blockIdx.x;
  const int head = bid & 31;
  const int qb = (bid < 256) ? (15 - (bid >> 5)) : ((bid >> 5) - 8);
  const int q0 = qb << 7;
  const size_t plane = (size_t)head * (SEQ * HDIM);
  const unsigned short* Qp = Qs + plane;
  const unsigned short* Kp = Ks + plane;
  const unsigned short* Vp = Vt + plane;

  // Q fragments (B-operand: col = c -> q-row)
  bf16x8 qf[2][4];
#pragma unroll
  for (int q2 = 0; q2 < 2; ++q2) {
    int s = q0 + w * 32 + q2 * 16 + c;
    int swb = (s & 7) << 3;
#pragma unroll
    for (int kk = 0; kk < 4; ++kk) {
      int d0 = kk * 32 + g * 8;
      qf[q2][kk] = *(const bf16x8*)(Qp + (size_t)s * HDIM + (d0 ^ swb));
    }
  }

  f32x4 accO[2][8];
#pragma unroll
  for (int i = 0; i < 2; ++i)
#pragma unroll
    for (int j = 0; j < 8; ++j) {
      accO[i][j][0] = 0.f; accO[i][j][1] = 0.f; accO[i][j][2] = 0.f; accO[i][j][3] = 0.f;
    }
  float mrun[2] = { -1e30f, -1e30f };
  float lrun[2] = { 0.f, 0.f };

  const char* KgBase = (const char*)Kp + (tid >> 4) * 256 + (tid & 15) * 16;
  const char* VgBase = (const char*)Vp + (size_t)(tid >> 3) * 4096 + (tid & 7) * 16;
  char* VldsW = (char*)Vlds + w * 1024;

  const int ntiles = (q0 >> 6) + 2;
  const int qminw = q0 + w * 32;
  const int qmaxw = qminw + 31;

  // Prologue: stage K(0) into buf 0
#pragma unroll
  for (int i = 0; i < 4; ++i)
    gl_lds16(KgBase, (char*)Klds[0] + w * 1024 + i * 4096), KgBase += 4096;
  KgBase -= 16384;

  for (int kt = 0; kt < ntiles; ++kt) {
    const int t0 = kt << 6;
    const bool havenext = (kt + 1 < ntiles);

    // Issue V(kt) then K(kt+1)
#pragma unroll
    for (int i = 0; i < 4; ++i)
      gl_lds16(VgBase + t0 * 2 + (size_t)i * 131072, VldsW + i * 4096);
    if (havenext) {
      char* kdst = (char*)Klds[(kt + 1) & 1] + w * 1024;
#pragma unroll
      for (int i = 0; i < 4; ++i)
        gl_lds16(KgBase + (size_t)(t0 + 64) * 256 + i * 4096, kdst + i * 4096);
    }
    // K(kt) landed: leave V(kt)+K(kt+1) in flight
    if (havenext) asm volatile("s_waitcnt vmcnt(8)" ::: "memory");
    else          asm volatile("s_waitcnt vmcnt(4)" ::: "memory");
    __builtin_amdgcn_s_barrier();

    if (t0 <= qmaxw) {
      const char* Kb = (const char*)Klds[kt & 1];
      f32x4 sacc[4][2];
#pragma unroll
      for (int i = 0; i < 4; ++i)
#pragma unroll
        for (int j = 0; j < 2; ++j) {
          sacc[i][j][0] = 0.f; sacc[i][j][1] = 0.f; sacc[i][j][2] = 0.f; sacc[i][j][3] = 0.f;
        }
      __builtin_amdgcn_s_setprio(1);
#pragma unroll
      for (int kk = 0; kk < 4; ++kk) {
        bf16x8 kf[4];
#pragma unroll
        for (int ta = 0; ta < 4; ++ta) {
          int t = ta * 16 + c;
          int d0 = kk * 32 + g * 8;
          kf[ta] = *(const bf16x8*)(Kb + t * 256 + ((d0 ^ ((t & 7) << 3)) << 1));
        }
#pragma unroll
        for (int ta = 0; ta < 4; ++ta)
#pragma unroll
          for (int q2 = 0; q2 < 2; ++q2)
            sacc[ta][q2] = mfma16(kf[ta], qf[q2][kk], sacc[ta][q2]);
      }
      __builtin_amdgcn_s_setprio(0);

      // causal mask: D[row=g*4+r -> t][col=c -> q]
      if (t0 + 63 > qminw) {
#pragma unroll
        for (int ta = 0; ta < 4; ++ta)
#pragma unroll
          for (int q2 = 0; q2 < 2; ++q2)
#pragma unroll
            for (int r = 0; r < 4; ++r) {
              int t = t0 + ta * 16 + g * 4 + r;
              int q = qminw + q2 * 16 + c;
              if (t > q) sacc[ta][q2][r] = -30000.f;
            }
      }

      // online softmax, per-lane q-chains (q = qminw + q2*16 + c)
      float corr[2];
      bool resc = false;
#pragma unroll
      for (int q2 = 0; q2 < 2; ++q2) {
        float mx = -30000.f;
#pragma unroll
        for (int ta = 0; ta < 4; ++ta)
          mx = fmaxf(mx, fmaxf(fmaxf(sacc[ta][q2][0], sacc[ta][q2][1]),
                               fmaxf(sacc[ta][q2][2], sacc[ta][q2][3])));
        mx = fmaxf(mx, __shfl_xor(mx, 16));
        mx = fmaxf(mx, __shfl_xor(mx, 32));
        bool rs = mx > mrun[q2] + 8.0f;   // T13 defer-max
        resc |= rs;
        float mnew = rs ? mx : mrun[q2];
        corr[q2] = fexp2(mrun[q2] - mnew);
        mrun[q2] = mnew;
        float ls = 0.f;
#pragma unroll
        for (int ta = 0; ta < 4; ++ta)
#pragma unroll
          for (int r = 0; r < 4; ++r) {
            float e = fexp2(sacc[ta][q2][r] - mnew);
            sacc[ta][q2][r] = e;
            ls += e;
          }
        ls += __shfl_xor(ls, 16);
        ls += __shfl_xor(ls, 32);
        lrun[q2] = lrun[q2] * corr[q2] + ls;
      }

      // rescale accO (rare after early tiles); corr lives in q=c domain,
      // accO rows are q = q2*16 + g*4 + r -> fetch via bpermute
      if (__any(resc)) {
#pragma unroll
        for (int q2 = 0; q2 < 2; ++q2)
#pragma unroll
          for (int r = 0; r < 4; ++r) {
            float cD = __shfl(corr[q2], (lane & 48) | (((lane >> 4) << 2) + r));
#pragma unroll
            for (int fn = 0; fn < 8; ++fn) accO[q2][fn][r] *= cD;
          }
      }

      // write P (bf16) rows [q][t], packed 4-wide
#pragma unroll
      for (int q2 = 0; q2 < 2; ++q2) {
        int prow = w * 32 + q2 * 16 + c;
#pragma unroll
        for (int ta = 0; ta < 4; ++ta) {
          u16x4 pk;
          pk[0] = f2bf(sacc[ta][q2][0]); pk[1] = f2bf(sacc[ta][q2][1]);
          pk[2] = f2bf(sacc[ta][q2][2]); pk[3] = f2bf(sacc[ta][q2][3]);
          *(u16x4*)(&Plds[prow * 72 + ta * 16 + g * 4]) = pk;
        }
      }
    }

    // V(kt) landed (K(kt+1) may still fly)
    if (havenext) asm volatile("s_waitcnt vmcnt(4)" ::: "memory");
    else          asm volatile("s_waitcnt vmcnt(0)" ::: "memory");
    __builtin_amdgcn_s_barrier();

    if (t0 <= qmaxw) {
      __builtin_amdgcn_s_setprio(1);
#pragma unroll
      for (int kk = 0; kk < 2; ++kk) {
        bf16x8 pa[2];
#pragma unroll
        for (int q2 = 0; q2 < 2; ++q2)
          pa[q2] = *(const bf16x8*)((const char*)Plds + (w * 32 + q2 * 16 + c) * 144 + (kk * 32 + g * 8) * 2);
#pragma unroll
        for (int fn = 0; fn < 8; ++fn) {
          int d = fn * 16 + c;
          int tt = kk * 32 + g * 8;
          bf16x8 vb = *(const bf16x8*)((const char*)Vlds + d * 128 + ((tt ^ ((d & 7) << 3)) << 1));
#pragma unroll
          for (int q2 = 0; q2 < 2; ++q2)
            accO[q2][fn] = mfma16(pa[q2], vb, accO[q2][fn]);
        }
      }
      __builtin_amdgcn_s_setprio(0);
    }
    __builtin_amdgcn_s_barrier();   // Vlds/Klds reads done before next stage
  }

  const int b = head >> 4, nh = head & 15;
  float linv[2] = { 1.0f / lrun[0], 1.0f / lrun[1] };
#pragma unroll
  for (int q2 = 0; q2 < 2; ++q2)
#pragma unroll
    for (int r = 0; r < 4; ++r) {
      float inv = __shfl(linv[q2], (lane & 48) | (((lane >> 4) << 2) + r));
      int q = q0 + w * 32 + q2 * 16 + g * 4 + r;
      int m = q * 2 + b;
      int swb = ((m >> 1) & 3) << 3;
#pragma unroll
      for (int fn = 0; fn < 8; ++fn) {
        int h = nh * 128 + fn * 16 + c;
        ctx[(size_t)m * HID + (h ^ swb)] = f2bf(accO[q2][fn][r] * inv);
      }
    }
}

extern "C" void kernel_launch(void* const* d_in, const int* in_sizes, int n_in,
                              void* d_out, int out_size, void* d_ws, size_t ws_size,
                              hipStream_t stream) {
  const float* hidden = (const float*)d_in[0];
  const float* Wqkv = (const float*)d_in[2];
  const float* bqkv = (const float*)d_in[3];
  const float* Wd   = (const float*)d_in[4];
  const float* bd   = (const float*)d_in[5];
  float* out = (float*)d_out;
  char* ws = (char*)d_ws;

  const size_t OFF_HID  = 0;
  const size_t OFF_WQKV = 16777216;
  const size_t OFF_WD   = 41943040;
  const size_t OFF_COS  = 50331648;
  const size_t OFF_SIN  = 50855936;
  const size_t OFF_Q    = 51380224;
  const size_t OFF_K    = 68157440;
  const size_t OFF_V    = 84934656;
  const size_t OFF_VT   = 101711872;
  if (ws_size < 118489088) return;

  unsigned short* hidb  = (unsigned short*)(ws + OFF_HID);
  unsigned short* wqkvb = (unsigned short*)(ws + OFF_WQKV);
  unsigned short* wdb   = (unsigned short*)(ws + OFF_WD);
  float* cosT = (float*)(ws + OFF_COS);
  float* sinT = (float*)(ws + OFF_SIN);
  unsigned short* Qsb = (unsigned short*)(ws + OFF_Q);
  unsigned short* Ksb = (unsigned short*)(ws + OFF_K);
  unsigned short* Vpb = (unsigned short*)(ws + OFF_V);
  unsigned short* Vtb = (unsigned short*)(ws + OFF_VT);
  unsigned short* ctxb = hidb;

  conv_swz<<<8192, 256, 0, stream>>>(hidden, hidb);
  conv_swz<<<12288, 256, 0, stream>>>(Wqkv, wqkvb);
  conv_swz<<<4096, 256, 0, stream>>>(Wd, wdb);
  rope_cache_k<<<512, 256, 0, stream>>>(cosT, sinT);

  gemm8p<0><<<dim3(24, 16), 512, 0, stream>>>(hidb, wqkvb, bqkv,
                                              Qsb, Ksb, Vpb, cosT, sinT, nullptr);
  transpose_v<<<1024, 256, 0, stream>>>(Vpb, Vtb);
  attn<<<512, 256, 0, stream>>>(Qsb, Ksb, Vtb, ctxb);
  gemm8p<1><<<dim3(8, 16), 512, 0, stream>>>(ctxb, wdb, bd,
                                             nullptr, nullptr, nullptr, nullptr, nullptr, out);
}